// Round 14
// baseline (327.357 us; speedup 1.0000x reference)
//
#include <hip/hip_runtime.h>
#include <math.h>

typedef __attribute__((ext_vector_type(8))) short bf16x8;
typedef __attribute__((ext_vector_type(4))) short bf16x4;
typedef __attribute__((ext_vector_type(4))) float f32x4;
typedef __attribute__((ext_vector_type(16))) float f32x16;

#define NH 12
#define HD 64
#define C0 768
#define C3 2304
#define LS 256
#define KT12 12

static __device__ __forceinline__ float bf2f(short u) {
  union { unsigned int i; float f; } c;
  c.i = ((unsigned int)(unsigned short)u) << 16;
  return c.f;
}
static __device__ __forceinline__ short f2bf(float f) {
  union { float f; unsigned int i; } c; c.f = f;
  unsigned int x = c.i;
  x += 0x7fffu + ((x >> 16) & 1u);
  return (short)(x >> 16);
}
static __device__ __forceinline__ unsigned pk2(float a, float b) {
  return (unsigned)(unsigned short)f2bf(a) | ((unsigned)(unsigned short)f2bf(b) << 16);
}

// async global->LDS, 16B per lane
static __device__ __forceinline__ void gload_lds16(const short* g, const short* l) {
  unsigned long long ga = (unsigned long long)g;
  unsigned int la = (unsigned int)(unsigned long long)l;
  __builtin_amdgcn_global_load_lds(
      (const __attribute__((address_space(1))) void*)ga,
      (__attribute__((address_space(3))) void*)la, 16, 0, 0);
}

// ---------------- cast + pack X -> A-fragment order (R10/R11 proven) ----------------
__global__ __launch_bounds__(256) void cast_pack_A_kernel(const float* __restrict__ x,
                                                          short* __restrict__ Apk) {
  __shared__ short sb[256 * 64];
  int bm = blockIdx.x, kt = blockIdx.y, t = threadIdx.x;
#pragma unroll
  for (int i = 0; i < 8; ++i) {
    int seg = i * 256 + t;
    int row = seg >> 3, sc8 = seg & 7;
    const float* src = x + ((long)(bm * 256 + row)) * C0 + kt * 64 + sc8 * 8;
    float4 v0 = *(const float4*)src;
    float4 v1 = *(const float4*)(src + 4);
    bf16x8 o = { f2bf(v0.x), f2bf(v0.y), f2bf(v0.z), f2bf(v0.w),
                 f2bf(v1.x), f2bf(v1.y), f2bf(v1.z), f2bf(v1.w) };
    *(bf16x8*)&sb[row * 64 + ((sc8 ^ (row & 7)) << 3)] = o;
  }
  __syncthreads();
#pragma unroll
  for (int i = 0; i < 8; ++i) {
    int c = i * 256 + t;
    int l = c & 63, f = c >> 6;
    int ks = f & 3, mt = (f >> 2) & 3, mh = f >> 4;
    int row = mh * 128 + mt * 32 + (l & 31);
    int kc = ks * 2 + (l >> 5);
    bf16x8 v = *(bf16x8*)&sb[row * 64 + ((kc ^ (row & 7)) << 3)];
    *(bf16x8*)&Apk[(((long)bm * KT12 + kt) * 2048 + c) * 8] = v;
  }
}

// ---------------- cast + pack W (fp32 [K][N]) -> B-fragment-packed bf16 ----------------
template <int WNG>
__global__ __launch_bounds__(256) void cast_pack_B_kernel(const float* __restrict__ w,
                                                          short* __restrict__ Bpk, int N) {
  __shared__ short sb[WNG * 64 * 64];  // [col][k]
  int bn = blockIdx.x, kt = blockIdx.y, t = threadIdx.x;
#pragma unroll
  for (int i = 0; i < WNG * 2; ++i) {
    int seg = i * 256 + t;
    int k = seg / (WNG * 8);
    int nc = (seg % (WNG * 8)) * 8;
    const float* src = w + ((long)(kt * 64 + k)) * N + bn * (WNG * 64) + nc;
    float4 v0 = *(const float4*)src;
    float4 v1 = *(const float4*)(src + 4);
    sb[(nc + 0) * 64 + k] = f2bf(v0.x); sb[(nc + 1) * 64 + k] = f2bf(v0.y);
    sb[(nc + 2) * 64 + k] = f2bf(v0.z); sb[(nc + 3) * 64 + k] = f2bf(v0.w);
    sb[(nc + 4) * 64 + k] = f2bf(v1.x); sb[(nc + 5) * 64 + k] = f2bf(v1.y);
    sb[(nc + 6) * 64 + k] = f2bf(v1.z); sb[(nc + 7) * 64 + k] = f2bf(v1.w);
  }
  __syncthreads();
#pragma unroll
  for (int i = 0; i < WNG * 2; ++i) {
    int c = i * 256 + t;
    int l = c & 63, f = c >> 6;
    int ks = f & 3, nt = (f >> 2) & 1, wng = f >> 3;
    int col = wng * 64 + nt * 32 + (l & 31);
    int kk = ks * 16 + (l >> 5) * 8;
    bf16x8 v = *(bf16x8*)&sb[col * 64 + kk];
    *(bf16x8*)&Bpk[(((long)bn * KT12 + kt) * (WNG * 512) + c) * 8] = v;
  }
}

// ---------------- RoPE table ----------------
__global__ void rope_tab_kernel(float* __restrict__ cost, float* __restrict__ sint) {
  int t = blockIdx.x, d = threadIdx.x;
  int i = d & 31;
  float freq = powf(10000.0f, -(float)(4 * i + 1) / 64.0f);
  float th = (float)t * freq;
  cost[t * 64 + d] = cosf(th);
  sint[t * 64 + d] = sinf(th);
}

// ---------------- 256x256 GEMM, 32x32x16, fragment-packed A+B (127-129 us measured) ----------------
#define PH_OPEN                                        \
  __builtin_amdgcn_s_barrier();                        \
  asm volatile("s_waitcnt lgkmcnt(0)" ::: "memory");   \
  __builtin_amdgcn_sched_barrier(0);                   \
  __builtin_amdgcn_s_setprio(1);
#define PH_MID __builtin_amdgcn_s_setprio(0);
#define PH_CLOSE                                       \
  asm volatile("s_waitcnt vmcnt(2)" ::: "memory");     \
  __builtin_amdgcn_s_barrier();
#define MM8(ASET, BSET, MP, NT)                                                     \
  { _Pragma("unroll") for (int m2_ = 0; m2_ < 2; ++m2_)                             \
      _Pragma("unroll") for (int ks_ = 0; ks_ < 4; ++ks_)                           \
        acc[(MP)*2 + m2_][NT] = __builtin_amdgcn_mfma_f32_32x32x16_bf16(            \
            ASET[m2_ * 4 + ks_], BSET[ks_], acc[(MP)*2 + m2_][NT], 0, 0, 0); }

__global__ __launch_bounds__(512, 2) void gemm32_kernel(const short* __restrict__ Apk,
                                                        const short* __restrict__ Bpk,
                                                        short* __restrict__ Cout,
                                                        int N, int nbn) {
  __shared__ short lds[65536];
  int t = threadIdx.x, lane = t & 63, wave = t >> 6;
  int wm = (wave >> 2) * 128, wng = wave & 3, wn = wng * 64, mh = wave >> 2;
  int id = blockIdx.x;
  int cpx = gridDim.x >> 3;
  int sw = (id & 7) * cpx + (id >> 3);
  int bm = sw / nbn, bn = sw % nbn;

  f32x16 acc[4][2];
#pragma unroll
  for (int m = 0; m < 4; ++m)
#pragma unroll
    for (int n = 0; n < 2; ++n)
#pragma unroll
      for (int r = 0; r < 16; ++r) acc[m][n][r] = 0.f;

  bf16x8 a0[8], a1[8], b0[4], b1[4];

  auto STAGE = [&](int s) {
    if (s >= 4 * KT12) return;
    int q = s & 3, Ts = s >> 2;
    int bb = (Ts & 1) * 32768;
    if (q < 2) {
      int c = q * 1024 + t;
      const short* src = Apk + ((long)bm * KT12 + Ts) * 16384 + (long)c * 8;
      gload_lds16(src, &lds[bb + c * 8]);
      gload_lds16(src + 4096, &lds[bb + (c + 512) * 8]);
    } else {
      int c = (q - 2) * 1024 + t;
      const short* src = Bpk + ((long)bn * KT12 + Ts) * 16384 + (long)c * 8;
      gload_lds16(src, &lds[bb + 16384 + c * 8]);
      gload_lds16(src + 4096, &lds[bb + 16384 + (c + 512) * 8]);
    }
  };
  auto LDA = [&](bf16x8* d, int b, int mhalf) {
#pragma unroll
    for (int m2 = 0; m2 < 2; ++m2)
#pragma unroll
      for (int ks = 0; ks < 4; ++ks)
        d[m2 * 4 + ks] =
            *(bf16x8*)&lds[b * 32768 + ((mh * 16 + (mhalf * 2 + m2) * 4 + ks) * 64 + lane) * 8];
  };
  auto LDB = [&](bf16x8* d, int b, int nt) {
#pragma unroll
    for (int ks = 0; ks < 4; ++ks)
      d[ks] = *(bf16x8*)&lds[b * 32768 + 16384 + ((wng * 8 + nt * 4 + ks) * 64 + lane) * 8];
  };

  for (int s = 0; s < 7; ++s) STAGE(s);
  asm volatile("s_waitcnt vmcnt(6)" ::: "memory");
  __builtin_amdgcn_s_barrier();
  LDA(a0, 0, 0);
  LDB(b0, 0, 0);
  LDB(b1, 0, 1);

  for (int it = 0; it < KT12 / 2; ++it) {
    int P0 = 8 * it;
    PH_OPEN; MM8(a0, b0, 0, 0); PH_MID;
    LDA(a1, 0, 1); STAGE(P0 + 7); PH_CLOSE;
    PH_OPEN; MM8(a0, b1, 0, 1); PH_MID;
    LDA(a0, 1, 0); STAGE(P0 + 8); PH_CLOSE;
    PH_OPEN; MM8(a1, b0, 1, 0); PH_MID;
    LDB(b0, 1, 0); STAGE(P0 + 9); PH_CLOSE;
    PH_OPEN; MM8(a1, b1, 1, 1); PH_MID;
    LDB(b1, 1, 1); STAGE(P0 + 10); PH_CLOSE;
    PH_OPEN; MM8(a0, b0, 0, 0); PH_MID;
    LDA(a1, 1, 1); STAGE(P0 + 11); PH_CLOSE;
    PH_OPEN; MM8(a0, b1, 0, 1); PH_MID;
    LDA(a0, 0, 0); STAGE(P0 + 12); PH_CLOSE;
    PH_OPEN; MM8(a1, b0, 1, 0); PH_MID;
    LDB(b0, 0, 0); STAGE(P0 + 13); PH_CLOSE;
    PH_OPEN; MM8(a1, b1, 1, 1); PH_MID;
    LDB(b1, 0, 1); STAGE(P0 + 14); PH_CLOSE;
  }

  long crow0 = (long)bm * 256 + wm;
  long ccol0 = (long)bn * 256 + wn;
  int rbase = 4 * (lane >> 5);
  int cl = lane & 31;
#pragma unroll
  for (int mt = 0; mt < 4; ++mt)
#pragma unroll
    for (int nt = 0; nt < 2; ++nt)
#pragma unroll
      for (int reg = 0; reg < 16; ++reg) {
        long row = crow0 + mt * 32 + (reg & 3) + 8 * (reg >> 2) + rbase;
        long col = ccol0 + nt * 32 + cl;
        Cout[row * N + col] = f2bf(acc[mt][nt][reg]);
      }
}

// ---------------- 128x128 GEMM, 32x32x16, m97 2-barrier loop, 2 blocks/CU (proj) ----------------
template <int OUT_F32>
__global__ __launch_bounds__(256, 2) void gemm128_kernel(const short* __restrict__ Arm,
                                                         const short* __restrict__ Bpk,
                                                         void* __restrict__ Cout,
                                                         int N, int K, int nbn) {
  __shared__ short lds[32768];
  int t = threadIdx.x, lane = t & 63, wave = t >> 6;
  int wm = (wave >> 1) * 64, wng = wave & 1;
  int id = blockIdx.x;
  int cpx = gridDim.x >> 3;
  int sw = (id & 7) * cpx + (id >> 3);
  int bm = sw / nbn, bn = sw % nbn;
  int l31 = lane & 31, lh = lane >> 5;

  f32x16 acc[2][2];
#pragma unroll
  for (int m = 0; m < 2; ++m)
#pragma unroll
    for (int n = 0; n < 2; ++n)
#pragma unroll
      for (int r = 0; r < 16; ++r) acc[m][n][r] = 0.f;

  auto STAGE = [&](int T) {
    int bb = (T & 1) * 16384;
#pragma unroll
    for (int i = 0; i < 4; ++i) {
      int q = i * 256 + t;
      int row = q >> 3, cp = q & 7;
      const short* ga = Arm + ((long)(bm * 128 + row)) * K + T * 64 + ((cp ^ (row & 7)) * 8);
      gload_lds16(ga, &lds[bb + q * 8]);
      const short* gb = Bpk + ((long)bn * KT12 + T) * 8192 + (long)q * 8;
      gload_lds16(gb, &lds[bb + 8192 + q * 8]);
    }
  };

  STAGE(0);
  asm volatile("s_waitcnt vmcnt(0)" ::: "memory");
  __builtin_amdgcn_s_barrier();

  for (int T = 0; T < KT12; ++T) {
    int bb = (T & 1) * 16384;
    if (T + 1 < KT12) STAGE(T + 1);
    bf16x8 a[2][4], b[2][4];
#pragma unroll
    for (int mt = 0; mt < 2; ++mt) {
      int row = wm + mt * 32 + l31;
      int s8 = row & 7;
#pragma unroll
      for (int ks = 0; ks < 4; ++ks) {
        int g = (ks * 2 + lh) ^ s8;
        a[mt][ks] = *(bf16x8*)&lds[bb + row * 64 + g * 8];
      }
    }
#pragma unroll
    for (int nt = 0; nt < 2; ++nt)
#pragma unroll
      for (int ks = 0; ks < 4; ++ks)
        b[nt][ks] = *(bf16x8*)&lds[bb + 8192 + (((wng * 2 + nt) * 4 + ks) * 64 + lane) * 8];
    __builtin_amdgcn_s_setprio(1);
#pragma unroll
    for (int mt = 0; mt < 2; ++mt)
#pragma unroll
      for (int nt = 0; nt < 2; ++nt)
#pragma unroll
        for (int ks = 0; ks < 4; ++ks)
          acc[mt][nt] = __builtin_amdgcn_mfma_f32_32x32x16_bf16(a[mt][ks], b[nt][ks],
                                                                acc[mt][nt], 0, 0, 0);
    __builtin_amdgcn_s_setprio(0);
    asm volatile("s_waitcnt lgkmcnt(0)" ::: "memory");
    asm volatile("s_waitcnt vmcnt(0)" ::: "memory");
    __builtin_amdgcn_s_barrier();
  }

  long crow0 = (long)bm * 128 + wm;
  long ccol0 = (long)bn * 128 + wng * 64;
  int rbase = 4 * lh;
#pragma unroll
  for (int mt = 0; mt < 2; ++mt)
#pragma unroll
    for (int nt = 0; nt < 2; ++nt)
#pragma unroll
      for (int reg = 0; reg < 16; ++reg) {
        long row = crow0 + mt * 32 + (reg & 3) + 8 * (reg >> 2) + rbase;
        long col = ccol0 + nt * 32 + l31;
        float v = acc[mt][nt][reg];
        if (OUT_F32) ((float*)Cout)[row * N + col] = v;
        else ((short*)Cout)[row * N + col] = f2bf(v);
      }
}

// ---------------- fused RMSNorm(q,k) + RoPE: one wave per (row, q/k) ----------------
__global__ __launch_bounds__(512) void norm_rope_kernel(short* __restrict__ QKV,
    const float* __restrict__ w_ln, const float* __restrict__ cost,
    const float* __restrict__ sint) {
  int wid = (blockIdx.x << 3) + (threadIdx.x >> 6);
  int lane = threadIdx.x & 63;
  int row = wid >> 1;
  int t = row & 255;
  long base = (long)row * C3 + (wid & 1) * C0;
  int e8 = lane * 8, e4 = 512 + lane * 4;
  bf16x8 v8 = *(const bf16x8*)&QKV[base + e8];
  bf16x4 v4 = *(const bf16x4*)&QKV[base + e4];
  float f[12];
#pragma unroll
  for (int j = 0; j < 8; ++j) f[j] = bf2f(v8[j]);
#pragma unroll
  for (int j = 0; j < 4; ++j) f[8 + j] = bf2f(v4[j]);
  float ss = 0.f;
#pragma unroll
  for (int j = 0; j < 12; ++j) ss += f[j] * f[j];
#pragma unroll
  for (int o = 32; o > 0; o >>= 1) ss += __shfl_xor(ss, o);
  float r = rsqrtf(ss * (1.0f / 768.0f) + 1e-6f);
  float4 w0 = *(const float4*)&w_ln[e8];
  float4 w1 = *(const float4*)&w_ln[e8 + 4];
  float4 w2 = *(const float4*)&w_ln[e4];
  float n[12];
  n[0] = f[0] * r * w0.x;  n[1] = f[1] * r * w0.y;
  n[2] = f[2] * r * w0.z;  n[3] = f[3] * r * w0.w;
  n[4] = f[4] * r * w1.x;  n[5] = f[5] * r * w1.y;
  n[6] = f[6] * r * w1.z;  n[7] = f[7] * r * w1.w;
  n[8] = f[8] * r * w2.x;  n[9] = f[9] * r * w2.y;
  n[10] = f[10] * r * w2.z; n[11] = f[11] * r * w2.w;
  int d8 = e8 & 63, d4 = e4 & 63;
  const float* cb = cost + t * 64;
  const float* sbp = sint + t * 64;
  float4 c0 = *(const float4*)&cb[d8], c1 = *(const float4*)&cb[d8 + 4];
  float4 c2 = *(const float4*)&cb[d4];
  float4 s0 = *(const float4*)&sbp[d8], s1 = *(const float4*)&sbp[d8 + 4];
  float4 s2 = *(const float4*)&sbp[d4];
  bf16x8 o8;
  bf16x4 o4;
  o8[0] = f2bf(n[0] * c0.x - n[1] * s0.x);
  o8[1] = f2bf(n[1] * c0.y + n[0] * s0.y);
  o8[2] = f2bf(n[2] * c0.z - n[3] * s0.z);
  o8[3] = f2bf(n[3] * c0.w + n[2] * s0.w);
  o8[4] = f2bf(n[4] * c1.x - n[5] * s1.x);
  o8[5] = f2bf(n[5] * c1.y + n[4] * s1.y);
  o8[6] = f2bf(n[6] * c1.z - n[7] * s1.z);
  o8[7] = f2bf(n[7] * c1.w + n[6] * s1.w);
  o4[0] = f2bf(n[8] * c2.x - n[9] * s2.x);
  o4[1] = f2bf(n[9] * c2.y + n[8] * s2.y);
  o4[2] = f2bf(n[10] * c2.z - n[11] * s2.z);
  o4[3] = f2bf(n[11] * c2.w + n[10] * s2.w);
  *(bf16x8*)&QKV[base + e8] = o8;
  *(bf16x4*)&QKV[base + e4] = o4;
}

// ---------------- block-causal attention (R7 staging + no-max softmax; R13 bench −7us) ----------------
__global__ __launch_bounds__(512, 3) void attn_kernel(const short* __restrict__ QKV,
                                                      short* __restrict__ Y) {
  __shared__ short Ks[256 * 64];
  __shared__ short Vt[64 * 256];
  int blk = blockIdx.x;
  int bg = blk / NH, h = blk % NH;
  const long base = (long)bg * LS * C3 + h * HD;
  int tid = threadIdx.x, lane = tid & 63, wave = tid >> 6;
  int lr = lane & 15, lg = lane >> 4;

#pragma unroll
  for (int it = 0; it < 4; ++it) {
    int q = it * 512 + tid;
    int row = q >> 3, cp = q & 7;
    int gcp = cp ^ (row & 7);
    gload_lds16(QKV + base + (long)row * C3 + C0 + gcp * 8, &Ks[q * 8]);
  }
#pragma unroll
  for (int it = 0; it < 8; ++it) {
    int e = tid * 4 + it * 2048;
    int k = e >> 6, n = e & 63;
    bf16x4 v = *(const bf16x4*)&QKV[base + (long)k * C3 + 2 * C0 + n];
#pragma unroll
    for (int j = 0; j < 4; ++j) {
      int nn = n + j;
      Vt[nn * 256 + (((k >> 3) ^ (nn & 7)) << 3) + (k & 7)] = v[j];
    }
  }
  asm volatile("s_waitcnt vmcnt(0)" ::: "memory");
  __syncthreads();

  int addrA = (((lane >> 4) & 1) * 32 + lr) * 4;
  int addrB = addrA + 64;
  bool selhi = (lane & 32) != 0;

  for (int tt = 0; tt < 2; ++tt) {
    int tile = (tt == 0) ? wave : (15 - wave);
    int m0 = tile * 16;
    bf16x8 qf[2];
#pragma unroll
    for (int ks = 0; ks < 2; ++ks)
      qf[ks] = *(const bf16x8*)&QKV[base + (long)(m0 + lr) * C3 + ks * 32 + lg * 8];

    f32x4 zero4 = {0.f, 0.f, 0.f, 0.f};
    f32x4 accs[16];
#pragma unroll
    for (int n = 0; n < 16; ++n) accs[n] = zero4;

    __builtin_amdgcn_s_setprio(1);
#pragma unroll
    for (int n = 0; n < 16; ++n) {
      if (n <= tile) {
        int row = n * 16 + lr, sw = row & 7;
        bf16x8 k0 = *(bf16x8*)&Ks[row * 64 + ((lg ^ sw) << 3)];
        bf16x8 k1 = *(bf16x8*)&Ks[row * 64 + (((4 + lg) ^ sw) << 3)];
        accs[n] = __builtin_amdgcn_mfma_f32_16x16x32_bf16(k0, qf[0], accs[n], 0, 0, 0);
        accs[n] = __builtin_amdgcn_mfma_f32_16x16x32_bf16(k1, qf[1], accs[n], 0, 0, 0);
      }
    }
    __builtin_amdgcn_s_setprio(0);

    // no-max softmax: diag mask then exp directly; tree-sum
    float ts[16];
#pragma unroll
    for (int n = 0; n < 16; ++n) {
      if (n <= tile) {
        if (n == tile) {
#pragma unroll
          for (int r = 0; r < 4; ++r)
            accs[n][r] = (lg * 4 + r <= lr) ? accs[n][r] : -1e30f;
        }
#pragma unroll
        for (int r = 0; r < 4; ++r) accs[n][r] = __expf(accs[n][r] * 0.125f);
        float s01 = accs[n][0] + accs[n][1];
        float s23 = accs[n][2] + accs[n][3];
        ts[n] = s01 + s23;
      } else {
        ts[n] = 0.f;
      }
    }
#pragma unroll
    for (int st = 1; st < 16; st <<= 1)
#pragma unroll
      for (int j = 0; j < 16; j += 2 * st) ts[j] += ts[j + st];
    float s = ts[0];
    s += __shfl_xor(s, 16);
    s += __shfl_xor(s, 32);
    float rs = 1.0f / s;
    float rv[4];
#pragma unroll
    for (int r = 0; r < 4; ++r) {
      union { float f; int i; } c; c.f = rs;
      union { int i; float f; } o;
      o.i = __builtin_amdgcn_ds_bpermute((lg * 4 + r) * 4, c.i);
      rv[r] = o.f;
    }

    int ktmax = (m0 + 15) >> 5;
    f32x4 yacc[4];
#pragma unroll
    for (int n2 = 0; n2 < 4; ++n2) yacc[n2] = zero4;
#pragma unroll
    for (int kt = 0; kt < 8; ++kt) {
      if (kt <= ktmax) {
        int n0 = 2 * kt, n1 = 2 * kt + 1;
        unsigned a01_0 = pk2(accs[n0][0], accs[n0][1]);
        unsigned a23_0 = pk2(accs[n0][2], accs[n0][3]);
        unsigned a01_1 = (n1 <= tile) ? pk2(accs[n1][0], accs[n1][1]) : 0u;
        unsigned a23_1 = (n1 <= tile) ? pk2(accs[n1][2], accs[n1][3]) : 0u;
        union { unsigned u[4]; bf16x8 v; } af;
        unsigned g0a = (unsigned)__builtin_amdgcn_ds_bpermute(addrA, (int)a01_0);
        unsigned g0b = (unsigned)__builtin_amdgcn_ds_bpermute(addrA, (int)a01_1);
        unsigned g1a = (unsigned)__builtin_amdgcn_ds_bpermute(addrA, (int)a23_0);
        unsigned g1b = (unsigned)__builtin_amdgcn_ds_bpermute(addrA, (int)a23_1);
        unsigned g2a = (unsigned)__builtin_amdgcn_ds_bpermute(addrB, (int)a01_0);
        unsigned g2b = (unsigned)__builtin_amdgcn_ds_bpermute(addrB, (int)a01_1);
        unsigned g3a = (unsigned)__builtin_amdgcn_ds_bpermute(addrB, (int)a23_0);
        unsigned g3b = (unsigned)__builtin_amdgcn_ds_bpermute(addrB, (int)a23_1);
        af.u[0] = selhi ? g0b : g0a;
        af.u[1] = selhi ? g1b : g1a;
        af.u[2] = selhi ? g2b : g2a;
        af.u[3] = selhi ? g3b : g3a;
        int ac = kt * 32 + lg * 8;
        __builtin_amdgcn_s_setprio(1);
#pragma unroll
        for (int n2 = 0; n2 < 4; ++n2) {
          int vn = n2 * 16 + lr;
          bf16x8 vb = *(bf16x8*)&Vt[vn * 256 + (((ac >> 3) ^ (vn & 7)) << 3)];
          yacc[n2] = __builtin_amdgcn_mfma_f32_16x16x32_bf16(af.v, vb, yacc[n2], 0, 0, 0);
        }
        __builtin_amdgcn_s_setprio(0);
      }
    }

#pragma unroll
    for (int n2 = 0; n2 < 4; ++n2) {
#pragma unroll
      for (int r = 0; r < 4; ++r) {
        int row = m0 + lg * 4 + r, d = n2 * 16 + lr;
        Y[((long)(bg * LS + row)) * C0 + h * HD + d] = f2bf(yacc[n2][r] * rv[r]);
      }
    }
  }
}

extern "C" void kernel_launch(void* const* d_in, const int* in_sizes, int n_in,
                              void* d_out, int out_size, void* d_ws, size_t ws_size,
                              hipStream_t stream) {
  (void)in_sizes; (void)n_in; (void)out_size; (void)ws_size;
  const float* x = (const float*)d_in[0];
  const float* w_qkv = (const float*)d_in[1];
  const float* w_ln = (const float*)d_in[2];
  const float* w_proj = (const float*)d_in[3];
  float* out = (float*)d_out;

  char* ws = (char*)d_ws;
  short* Apk     = (short*)(ws + 0);            // 50331648
  short* QKV     = (short*)(ws + 50331648);     // 150994944
  short* Yb      = (short*)(ws + 201326592);    // 50331648
  short* WqkvPk  = (short*)(ws + 251658240);    // 3538944 (packed WNG=4)
  short* WprojPk = (short*)(ws + 255197184);    // 1179648 (packed WNG=2)
  float* cost    = (float*)(ws + 256376832);
  float* sint    = (float*)(ws + 256442368);

  cast_pack_A_kernel<<<dim3(128, KT12), 256, 0, stream>>>(x, Apk);
  cast_pack_B_kernel<4><<<dim3(9, KT12), 256, 0, stream>>>(w_qkv, WqkvPk, C3);
  cast_pack_B_kernel<2><<<dim3(6, KT12), 256, 0, stream>>>(w_proj, WprojPk, C0);
  rope_tab_kernel<<<256, 64, 0, stream>>>(cost, sint);

  // QKV = X @ Wqkv : grid 128*9 = 1152 (%8==0), packed A + packed B
  gemm32_kernel<<<128 * 9, 512, 0, stream>>>(Apk, WqkvPk, QKV, C3, 9);
  norm_rope_kernel<<<8192, 512, 0, stream>>>(QKV, w_ln, cost, sint);
  attn_kernel<<<128 * NH, 512, 0, stream>>>(QKV, Yb);
  // out = Y @ Wproj : grid 1536 (%8==0), 128x128 tiles, 2 blocks/CU
  gemm128_kernel<1><<<256 * 6, 256, 0, stream>>>(Yb, WprojPk, out, C0, C0, 6);
}

// Round 15
// 312.756 us; speedup vs baseline: 1.0467x; 1.0467x over previous
//
#include <hip/hip_runtime.h>
#include <math.h>

typedef __attribute__((ext_vector_type(8))) short bf16x8;
typedef __attribute__((ext_vector_type(4))) short bf16x4;
typedef __attribute__((ext_vector_type(4))) float f32x4;
typedef __attribute__((ext_vector_type(16))) float f32x16;

#define NH 12
#define HD 64
#define C0 768
#define C3 2304
#define LS 256
#define KT12 12

static __device__ __forceinline__ float bf2f(short u) {
  union { unsigned int i; float f; } c;
  c.i = ((unsigned int)(unsigned short)u) << 16;
  return c.f;
}
static __device__ __forceinline__ short f2bf(float f) {
  union { float f; unsigned int i; } c; c.f = f;
  unsigned int x = c.i;
  x += 0x7fffu + ((x >> 16) & 1u);
  return (short)(x >> 16);
}
static __device__ __forceinline__ unsigned pk2(float a, float b) {
  return (unsigned)(unsigned short)f2bf(a) | ((unsigned)(unsigned short)f2bf(b) << 16);
}

// async global->LDS, 16B per lane
static __device__ __forceinline__ void gload_lds16(const short* g, const short* l) {
  unsigned long long ga = (unsigned long long)g;
  unsigned int la = (unsigned int)(unsigned long long)l;
  __builtin_amdgcn_global_load_lds(
      (const __attribute__((address_space(1))) void*)ga,
      (__attribute__((address_space(3))) void*)la, 16, 0, 0);
}

// ---------------- cast fp32 -> bf16 (vectorized) ----------------
__global__ __launch_bounds__(256) void cast_kernel(const float* __restrict__ in,
                                                   short* __restrict__ out, int nquads) {
  int i = blockIdx.x * blockDim.x + threadIdx.x;
  int stride = gridDim.x * blockDim.x;
  for (; i < nquads; i += stride) {
    float4 v = ((const float4*)in)[i];
    bf16x4 o = { f2bf(v.x), f2bf(v.y), f2bf(v.z), f2bf(v.w) };
    ((bf16x4*)out)[i] = o;
  }
}

// ---------------- cast + transpose: in[K][N] fp32 -> out[N][K] bf16 ----------------
__global__ __launch_bounds__(256) void cast_transpose_kernel(const float* __restrict__ in,
                                                             short* __restrict__ out,
                                                             int K, int N) {
  __shared__ float tile[32][33];
  int n0 = blockIdx.x * 32, k0 = blockIdx.y * 32;
  int tx = threadIdx.x & 31, ty = threadIdx.x >> 5;
#pragma unroll
  for (int i = 0; i < 32; i += 8)
    tile[ty + i][tx] = in[(long)(k0 + ty + i) * N + n0 + tx];
  __syncthreads();
#pragma unroll
  for (int i = 0; i < 32; i += 8)
    out[(long)(n0 + ty + i) * K + k0 + tx] = f2bf(tile[tx][ty + i]);
}

// ---------------- cast + pack W (fp32 [K][N]) -> B-fragment-packed bf16 ----------------
template <int WNG>
__global__ __launch_bounds__(256) void cast_pack_B_kernel(const float* __restrict__ w,
                                                          short* __restrict__ Bpk, int N) {
  __shared__ short sb[WNG * 64 * 64];  // [col][k]
  int bn = blockIdx.x, kt = blockIdx.y, t = threadIdx.x;
#pragma unroll
  for (int i = 0; i < WNG * 2; ++i) {
    int seg = i * 256 + t;
    int k = seg / (WNG * 8);
    int nc = (seg % (WNG * 8)) * 8;
    const float* src = w + ((long)(kt * 64 + k)) * N + bn * (WNG * 64) + nc;
    float4 v0 = *(const float4*)src;
    float4 v1 = *(const float4*)(src + 4);
    sb[(nc + 0) * 64 + k] = f2bf(v0.x); sb[(nc + 1) * 64 + k] = f2bf(v0.y);
    sb[(nc + 2) * 64 + k] = f2bf(v0.z); sb[(nc + 3) * 64 + k] = f2bf(v0.w);
    sb[(nc + 4) * 64 + k] = f2bf(v1.x); sb[(nc + 5) * 64 + k] = f2bf(v1.y);
    sb[(nc + 6) * 64 + k] = f2bf(v1.z); sb[(nc + 7) * 64 + k] = f2bf(v1.w);
  }
  __syncthreads();
#pragma unroll
  for (int i = 0; i < WNG * 2; ++i) {
    int c = i * 256 + t;
    int l = c & 63, f = c >> 6;
    int ks = f & 3, nt = (f >> 2) & 1, wng = f >> 3;
    int col = wng * 64 + nt * 32 + (l & 31);
    int kk = ks * 16 + (l >> 5) * 8;
    bf16x8 v = *(bf16x8*)&sb[col * 64 + kk];
    *(bf16x8*)&Bpk[(((long)bn * KT12 + kt) * (WNG * 512) + c) * 8] = v;
  }
}

// ---------------- RoPE table ----------------
__global__ void rope_tab_kernel(float* __restrict__ cost, float* __restrict__ sint) {
  int t = blockIdx.x, d = threadIdx.x;
  int i = d & 31;
  float freq = powf(10000.0f, -(float)(4 * i + 1) / 64.0f);
  float th = (float)t * freq;
  cost[t * 64 + d] = cosf(th);
  sint[t * 64 + d] = sinf(th);
}

// ---------------- 256x256 8-phase bf16 GEMM (round-6 exact, 135 us measured) ----------------
#define PH_PRE                                         \
  __builtin_amdgcn_s_barrier();                        \
  __builtin_amdgcn_s_setprio(1);
#define PH_POST                                        \
  __builtin_amdgcn_s_setprio(0);                       \
  asm volatile("s_waitcnt lgkmcnt(0)" ::: "memory");   \
  __builtin_amdgcn_s_barrier();
#define PH_POSTV                                       \
  __builtin_amdgcn_s_setprio(0);                       \
  asm volatile("s_waitcnt lgkmcnt(0)" ::: "memory");   \
  asm volatile("s_waitcnt vmcnt(4)" ::: "memory");     \
  __builtin_amdgcn_s_barrier();
#define MMQ(MH, NP)                                                                \
  { _Pragma("unroll") for (int f_ = 0; f_ < 4; ++f_)                               \
      _Pragma("unroll") for (int n_ = 0; n_ < 2; ++n_)                             \
        _Pragma("unroll") for (int k_ = 0; k_ < 2; ++k_)                           \
          acc[(MH)*4 + f_][(NP)*2 + n_] = __builtin_amdgcn_mfma_f32_16x16x32_bf16( \
              af[f_*2 + k_], bfv[((NP)*2 + n_)*2 + k_],                            \
              acc[(MH)*4 + f_][(NP)*2 + n_], 0, 0, 0); }

template <int OUT_F32>
__global__ __launch_bounds__(512, 2) void gemm8p_kernel(const short* __restrict__ A,
                                                        const short* __restrict__ Bt,
                                                        void* __restrict__ Cout,
                                                        int N, int K, int nbn) {
  __shared__ short lds[65536];
  int t = threadIdx.x, lane = t & 63, wave = t >> 6;
  int lr = lane & 15, lg = lane >> 4;
  int wm = (wave >> 2) * 128, wn = (wave & 3) * 64;
  int id = blockIdx.x;
  int cpx = gridDim.x >> 3;
  int sw = (id & 7) * cpx + (id >> 3);
  int bm = sw / nbn, bn = sw % nbn;
  const short* Abase = A + (long)bm * 256 * K;
  const short* Bbase = Bt + (long)bn * 256 * K;
  int srow = t >> 3;
  int scol = ((t & 7) ^ (srow & 7)) * 8;
  int smax = K >> 4;

  f32x4 acc[8][4];
#pragma unroll
  for (int m = 0; m < 8; ++m)
#pragma unroll
    for (int n = 0; n < 4; ++n) acc[m][n] = (f32x4){0.f, 0.f, 0.f, 0.f};

  bf16x8 af[8], bfv[8];

  auto STAGE = [&](int s) {
    int slot = s & 3;
    int Tg = (s < smax) ? (s >> 2) : 0;
    const short* base = (slot & 2) ? Abase : Bbase;
    const short* g = base + (long)((slot & 1) * 128 + srow) * K + Tg * 64 + scol;
    int lb = ((s >> 2) & 1) * 32768 + ((slot >> 1) ^ 1) * 16384 + (slot & 1) * 8192 + t * 8;
    gload_lds16(g, &lds[lb]);
    gload_lds16(g + (long)64 * K, &lds[lb + 4096]);
  };
  auto LDA = [&](int b, int mh) {
#pragma unroll
    for (int f = 0; f < 4; ++f) {
      int R = wm + mh * 64 + f * 16 + lr;
      int rb = b * 32768 + R * 64;
      int s8 = R & 7;
      af[f * 2 + 0] = *(bf16x8*)&lds[rb + ((lg ^ s8) << 3)];
      af[f * 2 + 1] = *(bf16x8*)&lds[rb + (((4 + lg) ^ s8) << 3)];
    }
  };
  auto LDB = [&](int b, int nh) {
#pragma unroll
    for (int j = 0; j < 2; ++j) {
      int R = wn + (nh * 2 + j) * 16 + lr;
      int rb = b * 32768 + 16384 + R * 64;
      int s8 = R & 7;
      bfv[(nh * 2 + j) * 2 + 0] = *(bf16x8*)&lds[rb + ((lg ^ s8) << 3)];
      bfv[(nh * 2 + j) * 2 + 1] = *(bf16x8*)&lds[rb + (((4 + lg) ^ s8) << 3)];
    }
  };

  STAGE(0); STAGE(1); STAGE(2); STAGE(3); STAGE(4); STAGE(5);
  asm volatile("s_waitcnt vmcnt(4)" ::: "memory");
  __builtin_amdgcn_s_barrier();

  int iters = K >> 7;
  for (int i = 0; i < iters; ++i) {
    int si = 8 * i + 6;
    LDA(0, 0); LDB(0, 0);
    STAGE(si + 0);
    PH_PRE; MMQ(0, 0); PH_POST;
    LDB(0, 1);
    STAGE(si + 1);
    PH_PRE; MMQ(0, 1); PH_POST;
    LDA(0, 1);
    STAGE(si + 2);
    PH_PRE; MMQ(1, 0); PH_POST;
    STAGE(si + 3);
    PH_PRE; MMQ(1, 1); PH_POSTV;
    LDA(1, 0); LDB(1, 0);
    STAGE(si + 4);
    PH_PRE; MMQ(0, 0); PH_POST;
    LDB(1, 1);
    STAGE(si + 5);
    PH_PRE; MMQ(0, 1); PH_POST;
    LDA(1, 1);
    STAGE(si + 6);
    PH_PRE; MMQ(1, 0); PH_POST;
    STAGE(si + 7);
    PH_PRE; MMQ(1, 1); PH_POSTV;
  }

  long crow0 = (long)bm * 256 + wm;
  long ccol0 = (long)bn * 256 + wn;
#pragma unroll
  for (int f = 0; f < 8; ++f)
#pragma unroll
    for (int n = 0; n < 4; ++n)
#pragma unroll
      for (int r = 0; r < 4; ++r) {
        long row = crow0 + (f >> 2) * 64 + (f & 3) * 16 + lg * 4 + r;
        long col = ccol0 + n * 16 + lr;
        float v = acc[f][n][r];
        if (OUT_F32) ((float*)Cout)[row * N + col] = v;
        else ((short*)Cout)[row * N + col] = f2bf(v);
      }
}

// ---------------- 128x128 GEMM, 32x32x16, m97 2-barrier loop, 2 blocks/CU (proj) ----------------
template <int OUT_F32>
__global__ __launch_bounds__(256, 2) void gemm128_kernel(const short* __restrict__ Arm,
                                                         const short* __restrict__ Bpk,
                                                         void* __restrict__ Cout,
                                                         int N, int K, int nbn) {
  __shared__ short lds[32768];
  int t = threadIdx.x, lane = t & 63, wave = t >> 6;
  int wm = (wave >> 1) * 64, wng = wave & 1;
  int id = blockIdx.x;
  int cpx = gridDim.x >> 3;
  int sw = (id & 7) * cpx + (id >> 3);
  int bm = sw / nbn, bn = sw % nbn;
  int l31 = lane & 31, lh = lane >> 5;

  f32x16 acc[2][2];
#pragma unroll
  for (int m = 0; m < 2; ++m)
#pragma unroll
    for (int n = 0; n < 2; ++n)
#pragma unroll
      for (int r = 0; r < 16; ++r) acc[m][n][r] = 0.f;

  auto STAGE = [&](int T) {
    int bb = (T & 1) * 16384;
#pragma unroll
    for (int i = 0; i < 4; ++i) {
      int q = i * 256 + t;
      int row = q >> 3, cp = q & 7;
      const short* ga = Arm + ((long)(bm * 128 + row)) * K + T * 64 + ((cp ^ (row & 7)) * 8);
      gload_lds16(ga, &lds[bb + q * 8]);
      const short* gb = Bpk + ((long)bn * KT12 + T) * 8192 + (long)q * 8;
      gload_lds16(gb, &lds[bb + 8192 + q * 8]);
    }
  };

  STAGE(0);
  asm volatile("s_waitcnt vmcnt(0)" ::: "memory");
  __builtin_amdgcn_s_barrier();

  for (int T = 0; T < KT12; ++T) {
    int bb = (T & 1) * 16384;
    if (T + 1 < KT12) STAGE(T + 1);
    bf16x8 a[2][4], b[2][4];
#pragma unroll
    for (int mt = 0; mt < 2; ++mt) {
      int row = wm + mt * 32 + l31;
      int s8 = row & 7;
#pragma unroll
      for (int ks = 0; ks < 4; ++ks) {
        int g = (ks * 2 + lh) ^ s8;
        a[mt][ks] = *(bf16x8*)&lds[bb + row * 64 + g * 8];
      }
    }
#pragma unroll
    for (int nt = 0; nt < 2; ++nt)
#pragma unroll
      for (int ks = 0; ks < 4; ++ks)
        b[nt][ks] = *(bf16x8*)&lds[bb + 8192 + (((wng * 2 + nt) * 4 + ks) * 64 + lane) * 8];
    __builtin_amdgcn_s_setprio(1);
#pragma unroll
    for (int mt = 0; mt < 2; ++mt)
#pragma unroll
      for (int nt = 0; nt < 2; ++nt)
#pragma unroll
        for (int ks = 0; ks < 4; ++ks)
          acc[mt][nt] = __builtin_amdgcn_mfma_f32_32x32x16_bf16(a[mt][ks], b[nt][ks],
                                                                acc[mt][nt], 0, 0, 0);
    __builtin_amdgcn_s_setprio(0);
    asm volatile("s_waitcnt lgkmcnt(0)" ::: "memory");
    asm volatile("s_waitcnt vmcnt(0)" ::: "memory");
    __builtin_amdgcn_s_barrier();
  }

  long crow0 = (long)bm * 128 + wm;
  long ccol0 = (long)bn * 128 + wng * 64;
  int rbase = 4 * lh;
#pragma unroll
  for (int mt = 0; mt < 2; ++mt)
#pragma unroll
    for (int nt = 0; nt < 2; ++nt)
#pragma unroll
      for (int reg = 0; reg < 16; ++reg) {
        long row = crow0 + mt * 32 + (reg & 3) + 8 * (reg >> 2) + rbase;
        long col = ccol0 + nt * 32 + l31;
        float v = acc[mt][nt][reg];
        if (OUT_F32) ((float*)Cout)[row * N + col] = v;
        else ((short*)Cout)[row * N + col] = f2bf(v);
      }
}

// ---------------- fused RMSNorm(q,k) + RoPE: one wave per (row, q/k) ----------------
__global__ __launch_bounds__(512) void norm_rope_kernel(short* __restrict__ QKV,
    const float* __restrict__ w_ln, const float* __restrict__ cost,
    const float* __restrict__ sint) {
  int wid = (blockIdx.x << 3) + (threadIdx.x >> 6);
  int lane = threadIdx.x & 63;
  int row = wid >> 1;
  int t = row & 255;
  long base = (long)row * C3 + (wid & 1) * C0;
  int e8 = lane * 8, e4 = 512 + lane * 4;
  bf16x8 v8 = *(const bf16x8*)&QKV[base + e8];
  bf16x4 v4 = *(const bf16x4*)&QKV[base + e4];
  float f[12];
#pragma unroll
  for (int j = 0; j < 8; ++j) f[j] = bf2f(v8[j]);
#pragma unroll
  for (int j = 0; j < 4; ++j) f[8 + j] = bf2f(v4[j]);
  float ss = 0.f;
#pragma unroll
  for (int j = 0; j < 12; ++j) ss += f[j] * f[j];
#pragma unroll
  for (int o = 32; o > 0; o >>= 1) ss += __shfl_xor(ss, o);
  float r = rsqrtf(ss * (1.0f / 768.0f) + 1e-6f);
  float4 w0 = *(const float4*)&w_ln[e8];
  float4 w1 = *(const float4*)&w_ln[e8 + 4];
  float4 w2 = *(const float4*)&w_ln[e4];
  float n[12];
  n[0] = f[0] * r * w0.x;  n[1] = f[1] * r * w0.y;
  n[2] = f[2] * r * w0.z;  n[3] = f[3] * r * w0.w;
  n[4] = f[4] * r * w1.x;  n[5] = f[5] * r * w1.y;
  n[6] = f[6] * r * w1.z;  n[7] = f[7] * r * w1.w;
  n[8] = f[8] * r * w2.x;  n[9] = f[9] * r * w2.y;
  n[10] = f[10] * r * w2.z; n[11] = f[11] * r * w2.w;
  int d8 = e8 & 63, d4 = e4 & 63;
  const float* cb = cost + t * 64;
  const float* sbp = sint + t * 64;
  float4 c0 = *(const float4*)&cb[d8], c1 = *(const float4*)&cb[d8 + 4];
  float4 c2 = *(const float4*)&cb[d4];
  float4 s0 = *(const float4*)&sbp[d8], s1 = *(const float4*)&sbp[d8 + 4];
  float4 s2 = *(const float4*)&sbp[d4];
  bf16x8 o8;
  bf16x4 o4;
  o8[0] = f2bf(n[0] * c0.x - n[1] * s0.x);
  o8[1] = f2bf(n[1] * c0.y + n[0] * s0.y);
  o8[2] = f2bf(n[2] * c0.z - n[3] * s0.z);
  o8[3] = f2bf(n[3] * c0.w + n[2] * s0.w);
  o8[4] = f2bf(n[4] * c1.x - n[5] * s1.x);
  o8[5] = f2bf(n[5] * c1.y + n[4] * s1.y);
  o8[6] = f2bf(n[6] * c1.z - n[7] * s1.z);
  o8[7] = f2bf(n[7] * c1.w + n[6] * s1.w);
  o4[0] = f2bf(n[8] * c2.x - n[9] * s2.x);
  o4[1] = f2bf(n[9] * c2.y + n[8] * s2.y);
  o4[2] = f2bf(n[10] * c2.z - n[11] * s2.z);
  o4[3] = f2bf(n[11] * c2.w + n[10] * s2.w);
  *(bf16x8*)&QKV[base + e8] = o8;
  *(bf16x4*)&QKV[base + e4] = o4;
}

// ---------------- block-causal attention (R7 staging + no-max softmax) ----------------
__global__ __launch_bounds__(512, 3) void attn_kernel(const short* __restrict__ QKV,
                                                      short* __restrict__ Y) {
  __shared__ short Ks[256 * 64];
  __shared__ short Vt[64 * 256];
  int blk = blockIdx.x;
  int bg = blk / NH, h = blk % NH;
  const long base = (long)bg * LS * C3 + h * HD;
  int tid = threadIdx.x, lane = tid & 63, wave = tid >> 6;
  int lr = lane & 15, lg = lane >> 4;

#pragma unroll
  for (int it = 0; it < 4; ++it) {
    int q = it * 512 + tid;
    int row = q >> 3, cp = q & 7;
    int gcp = cp ^ (row & 7);
    gload_lds16(QKV + base + (long)row * C3 + C0 + gcp * 8, &Ks[q * 8]);
  }
#pragma unroll
  for (int it = 0; it < 8; ++it) {
    int e = tid * 4 + it * 2048;
    int k = e >> 6, n = e & 63;
    bf16x4 v = *(const bf16x4*)&QKV[base + (long)k * C3 + 2 * C0 + n];
#pragma unroll
    for (int j = 0; j < 4; ++j) {
      int nn = n + j;
      Vt[nn * 256 + (((k >> 3) ^ (nn & 7)) << 3) + (k & 7)] = v[j];
    }
  }
  asm volatile("s_waitcnt vmcnt(0)" ::: "memory");
  __syncthreads();

  int addrA = (((lane >> 4) & 1) * 32 + lr) * 4;
  int addrB = addrA + 64;
  bool selhi = (lane & 32) != 0;

  for (int tt = 0; tt < 2; ++tt) {
    int tile = (tt == 0) ? wave : (15 - wave);
    int m0 = tile * 16;
    bf16x8 qf[2];
#pragma unroll
    for (int ks = 0; ks < 2; ++ks)
      qf[ks] = *(const bf16x8*)&QKV[base + (long)(m0 + lr) * C3 + ks * 32 + lg * 8];

    f32x4 zero4 = {0.f, 0.f, 0.f, 0.f};
    f32x4 accs[16];
#pragma unroll
    for (int n = 0; n < 16; ++n) accs[n] = zero4;

    __builtin_amdgcn_s_setprio(1);
#pragma unroll
    for (int n = 0; n < 16; ++n) {
      if (n <= tile) {
        int row = n * 16 + lr, sw = row & 7;
        bf16x8 k0 = *(bf16x8*)&Ks[row * 64 + ((lg ^ sw) << 3)];
        bf16x8 k1 = *(bf16x8*)&Ks[row * 64 + (((4 + lg) ^ sw) << 3)];
        accs[n] = __builtin_amdgcn_mfma_f32_16x16x32_bf16(k0, qf[0], accs[n], 0, 0, 0);
        accs[n] = __builtin_amdgcn_mfma_f32_16x16x32_bf16(k1, qf[1], accs[n], 0, 0, 0);
      }
    }
    __builtin_amdgcn_s_setprio(0);

    // no-max softmax: diag mask then exp directly; tree-sum
    float ts[16];
#pragma unroll
    for (int n = 0; n < 16; ++n) {
      if (n <= tile) {
        if (n == tile) {
#pragma unroll
          for (int r = 0; r < 4; ++r)
            accs[n][r] = (lg * 4 + r <= lr) ? accs[n][r] : -1e30f;
        }
#pragma unroll
        for (int r = 0; r < 4; ++r) accs[n][r] = __expf(accs[n][r] * 0.125f);
        float s01 = accs[n][0] + accs[n][1];
        float s23 = accs[n][2] + accs[n][3];
        ts[n] = s01 + s23;
      } else {
        ts[n] = 0.f;
      }
    }
#pragma unroll
    for (int st = 1; st < 16; st <<= 1)
#pragma unroll
      for (int j = 0; j < 16; j += 2 * st) ts[j] += ts[j + st];
    float s = ts[0];
    s += __shfl_xor(s, 16);
    s += __shfl_xor(s, 32);
    float rs = 1.0f / s;
    float rv[4];
#pragma unroll
    for (int r = 0; r < 4; ++r) {
      union { float f; int i; } c; c.f = rs;
      union { int i; float f; } o;
      o.i = __builtin_amdgcn_ds_bpermute((lg * 4 + r) * 4, c.i);
      rv[r] = o.f;
    }

    int ktmax = (m0 + 15) >> 5;
    f32x4 yacc[4];
#pragma unroll
    for (int n2 = 0; n2 < 4; ++n2) yacc[n2] = zero4;
#pragma unroll
    for (int kt = 0; kt < 8; ++kt) {
      if (kt <= ktmax) {
        int n0 = 2 * kt, n1 = 2 * kt + 1;
        unsigned a01_0 = pk2(accs[n0][0], accs[n0][1]);
        unsigned a23_0 = pk2(accs[n0][2], accs[n0][3]);
        unsigned a01_1 = (n1 <= tile) ? pk2(accs[n1][0], accs[n1][1]) : 0u;
        unsigned a23_1 = (n1 <= tile) ? pk2(accs[n1][2], accs[n1][3]) : 0u;
        union { unsigned u[4]; bf16x8 v; } af;
        unsigned g0a = (unsigned)__builtin_amdgcn_ds_bpermute(addrA, (int)a01_0);
        unsigned g0b = (unsigned)__builtin_amdgcn_ds_bpermute(addrA, (int)a01_1);
        unsigned g1a = (unsigned)__builtin_amdgcn_ds_bpermute(addrA, (int)a23_0);
        unsigned g1b = (unsigned)__builtin_amdgcn_ds_bpermute(addrA, (int)a23_1);
        unsigned g2a = (unsigned)__builtin_amdgcn_ds_bpermute(addrB, (int)a01_0);
        unsigned g2b = (unsigned)__builtin_amdgcn_ds_bpermute(addrB, (int)a01_1);
        unsigned g3a = (unsigned)__builtin_amdgcn_ds_bpermute(addrB, (int)a23_0);
        unsigned g3b = (unsigned)__builtin_amdgcn_ds_bpermute(addrB, (int)a23_1);
        af.u[0] = selhi ? g0b : g0a;
        af.u[1] = selhi ? g1b : g1a;
        af.u[2] = selhi ? g2b : g2a;
        af.u[3] = selhi ? g3b : g3a;
        int ac = kt * 32 + lg * 8;
        __builtin_amdgcn_s_setprio(1);
#pragma unroll
        for (int n2 = 0; n2 < 4; ++n2) {
          int vn = n2 * 16 + lr;
          bf16x8 vb = *(bf16x8*)&Vt[vn * 256 + (((ac >> 3) ^ (vn & 7)) << 3)];
          yacc[n2] = __builtin_amdgcn_mfma_f32_16x16x32_bf16(af.v, vb, yacc[n2], 0, 0, 0);
        }
        __builtin_amdgcn_s_setprio(0);
      }
    }

#pragma unroll
    for (int n2 = 0; n2 < 4; ++n2) {
#pragma unroll
      for (int r = 0; r < 4; ++r) {
        int row = m0 + lg * 4 + r, d = n2 * 16 + lr;
        Y[((long)(bg * LS + row)) * C0 + h * HD + d] = f2bf(yacc[n2][r] * rv[r]);
      }
    }
  }
}

extern "C" void kernel_launch(void* const* d_in, const int* in_sizes, int n_in,
                              void* d_out, int out_size, void* d_ws, size_t ws_size,
                              hipStream_t stream) {
  (void)in_sizes; (void)n_in; (void)out_size; (void)ws_size;
  const float* x = (const float*)d_in[0];
  const float* w_qkv = (const float*)d_in[1];
  const float* w_ln = (const float*)d_in[2];
  const float* w_proj = (const float*)d_in[3];
  float* out = (float*)d_out;

  char* ws = (char*)d_ws;
  short* Xb      = (short*)(ws + 0);            // 50331648
  short* QKV     = (short*)(ws + 50331648);     // 150994944
  short* Yb      = (short*)(ws + 201326592);    // 50331648
  short* WqkvT   = (short*)(ws + 251658240);    // 3538944 ([2304][768] bf16)
  short* WprojPk = (short*)(ws + 255197184);    // 1179648 (packed WNG=2)
  float* cost    = (float*)(ws + 256376832);
  float* sint    = (float*)(ws + 256442368);

  cast_kernel<<<2048, 256, 0, stream>>>(x, Xb, (4 * 8192 * C0) / 4);
  cast_transpose_kernel<<<dim3(C3 / 32, C0 / 32), 256, 0, stream>>>(w_qkv, WqkvT, C0, C3);
  cast_pack_B_kernel<2><<<dim3(6, KT12), 256, 0, stream>>>(w_proj, WprojPk, C0);
  rope_tab_kernel<<<256, 64, 0, stream>>>(cost, sint);

  // QKV = X @ Wqkv : grid 9*128 = 1152 (%8==0)
  gemm8p_kernel<0><<<(C3 / 256) * (32768 / 256), 512, 0, stream>>>(Xb, WqkvT, QKV,
                                                                   C3, C0, C3 / 256);
  // RMSNorm+RoPE: 65536 waves / 8 per block
  norm_rope_kernel<<<8192, 512, 0, stream>>>(QKV, w_ln, cost, sint);
  attn_kernel<<<128 * NH, 512, 0, stream>>>(QKV, Yb);
  // out = Y @ Wproj : grid 1536 (%8==0), 128x128 tiles, 2 blocks/CU
  gemm128_kernel<1><<<256 * 6, 256, 0, stream>>>(Yb, WprojPk, out, C0, C0, 6);
}